// Round 14
// baseline (968.700 us; speedup 1.0000x reference)
//
#include <hip/hip_runtime.h>
#include <stdint.h>

// Persistent-kernel RNN: 256 wgs (1/CU), h exchanged via MALL + per-group flags.
// R16 = R15 (GB=32 x GJ=8, register-resident W, direct-global A bursts — PASSED
// 968us, best) + R7-PROVEN L2-cached A loads.
//  R15 analysis: halving read volume (GJ 16->8) gave -16%, sub-linear => the
//  residual floor is the serialized latency chain (~3 MALL RTTs/step). The A
//  burst is the one hop with a cheaper legal path: all 8 peers of a bg are
//  blockIdx == bg (mod 32) -> same XCD (round-robin %8). Producers' sc0 sc1
//  h-stores write THROUGH the local L2 (update/invalidate en route to MALL),
//  so consumer A loads go PLAIN (L1/L2-cacheable, ~250cy L2 hit vs ~900cy
//  MALL) with one buffer_inv sc0 (private per-CU L1 inv) per step.
//  This combo (plain loads + L1-only inv + sc0sc1 producers) PASSED in R7 on
//  the same same-XCD-peers property; R15's burst structure is A-latency-bound
//  where R7's wasn't. Staleness would fail absmax loudly, not hang.
// Everything else byte-identical to R15: barr[8][8] register W, tied "+v"
// vmcnt wait + sched_barrier (R11 lesson), lane-contiguous f32x4 scratch,
// R2 flag protocol + per-launch flag memset, fixed issue4_16 head staging.
// Lessons kept: sc0-only spin hangs (R3); buffer_inv sc1 = L2 nuke (R4);
// data-polling retry storms (R5/R9); scope bits don't change cost (R5==R6).

#define BATCH 512
#define SEQ   256
#define HID   1024
#define CLS   128

#define GB 32          // batch groups
#define GJ 8           // hidden slices (consumers per h byte)
#define BT 16          // batch rows per wg
#define JT 128         // hidden cols per wg
#define HSTR 132       // h exchange row stride (halves)
#define HS_OFF 16384   // halves: hS overlay at byte 32768 (above 32KB scratch)
#define SMEM_BYTES (32768 + BT * HSTR * 2)   // 36992 B
#define HBUF_HALVES (BATCH * HID)            // 1 MB per buffer

typedef __attribute__((ext_vector_type(8))) short  bf16x8;
typedef __attribute__((ext_vector_type(4))) short  s16x4;
typedef __attribute__((ext_vector_type(4))) float  f32x4;
typedef __attribute__((ext_vector_type(4))) int    i32x4;
typedef __attribute__((ext_vector_type(2))) unsigned int u32x2;

__device__ __forceinline__ unsigned short f2bf(float f) {
  unsigned int u = __float_as_uint(f);
  u = (u + 0x7FFFu + ((u >> 16) & 1u)) >> 16;   // RNE
  return (unsigned short)u;
}
__device__ __forceinline__ float b2f(short h) {
  return __uint_as_float(((unsigned int)(unsigned short)h) << 16);
}

// ---- device-coherent (MALL) protocol accesses ----
__device__ __forceinline__ void store_flag(int* p, int v) {
  asm volatile("global_store_dword %0, %1, off sc0 sc1" :: "v"(p), "v"(v) : "memory");
}
__device__ __forceinline__ int load_flag(const int* p) {
  int v;
  asm volatile("global_load_dword %0, %1, off sc0 sc1\n\t"
               "s_waitcnt vmcnt(0)" : "=v"(v) : "v"(p) : "memory");
  return v;
}
__device__ __forceinline__ void store16(void* p, i32x4 v) {
  asm volatile("global_store_dwordx4 %0, %1, off sc0 sc1" :: "v"(p), "v"(v) : "memory");
}
__device__ __forceinline__ void waitcnt0() {
  asm volatile("s_waitcnt vmcnt(0)" ::: "memory");
}
// private per-CU L1 invalidate (sc0 ONLY — not R4's shared-L2 nuke), drained
// in-asm so the following __syncthreads orders it before every wave's A loads.
__device__ __forceinline__ void l1_inv_wait() {
  asm volatile("buffer_inv sc0\n\ts_waitcnt vmcnt(0)" ::: "memory");
}
// raw workgroup barrier: drains LDS ops only
__device__ __forceinline__ void barrier_lgkm() {
  asm volatile("s_waitcnt lgkmcnt(0)\n\ts_barrier" ::: "memory");
}
// 4x dwordx4 PLAIN (L1/L2-cacheable) loads, 64B apart — A-fragment path.
// Fresh because: L1 invalidated this step; same-XCD L2 updated by producers'
// sc0 sc1 write-through (flag observed => stores completed). [R7-verified]
__device__ __forceinline__ void issue4_64(const void* p, i32x4& a, i32x4& b, i32x4& c, i32x4& d) {
  asm volatile(
    "global_load_dwordx4 %0, %4, off\n\t"
    "global_load_dwordx4 %1, %4, off offset:64\n\t"
    "global_load_dwordx4 %2, %4, off offset:128\n\t"
    "global_load_dwordx4 %3, %4, off offset:192"
    : "=&v"(a), "=&v"(b), "=&v"(c), "=&v"(d)
    : "v"(p) : "memory");
}
// 4x dwordx4 coherent loads, 16B apart (contiguous 64 B — head staging)
__device__ __forceinline__ void issue4_16(const void* p, i32x4& a, i32x4& b, i32x4& c, i32x4& d) {
  asm volatile(
    "global_load_dwordx4 %0, %4, off sc0 sc1\n\t"
    "global_load_dwordx4 %1, %4, off offset:16 sc0 sc1\n\t"
    "global_load_dwordx4 %2, %4, off offset:32 sc0 sc1\n\t"
    "global_load_dwordx4 %3, %4, off offset:48 sc0 sc1"
    : "=&v"(a), "=&v"(b), "=&v"(c), "=&v"(d)
    : "v"(p) : "memory");
}

__device__ __forceinline__ void wr16(short* p, i32x4 v) {  // 16 B to LDS as 2x b64
  u32x2 lo, hi;
  lo.x = (unsigned)v.x; lo.y = (unsigned)v.y;
  hi.x = (unsigned)v.z; hi.y = (unsigned)v.w;
  *(u32x2*)p = lo;
  *(u32x2*)(p + 4) = hi;
}
__device__ __forceinline__ float tanh_fast(float z) {
  float e = __expf(2.f * z);
  return 1.f - 2.f / (e + 1.f);
}

#define MFMA(a, b, c) __builtin_amdgcn_mfma_f32_16x16x32_bf16((a), (b), (c), 0, 0, 0)

__global__ void __launch_bounds__(256, 1)
rnn_persistent(const float* __restrict__ x, const float* __restrict__ Whx,
               const float* __restrict__ Whh, const float* __restrict__ bh,
               const float* __restrict__ Wph, const float* __restrict__ bp,
               float* __restrict__ out, unsigned short* hbuf, int* flags)
{
  extern __shared__ short smem[];
  float* scr = (float*)smem;            // 32KB reduction scratch (head reuses)
  short* hS  = smem + HS_OFF;           // [BT][HSTR] exchange overlay

  const int tid  = threadIdx.x;
  const int bg   = blockIdx.x & 31;     // 32 batch groups
  const int jg   = blockIdx.x >> 5;     // 8 hidden slices
  const int lane = tid & 63;
  const int wv   = tid >> 6;            // wave = k-quarter owner
  const int l15  = lane & 15;
  const int quad = lane >> 4;

  // ---- W_hh into REGISTERS: cols jg*128+ct*16+l15, k = wv*256+ks*32+quad*8 ----
  bf16x8 barr[8][8];                    // 256 VGPR
#pragma unroll
  for (int ct = 0; ct < 8; ++ct) {
#pragma unroll
    for (int ks = 0; ks < 8; ++ks) {
      const float* wp = Whh + (jg * JT + ct * 16 + l15) * HID
                            + wv * 256 + ks * 32 + quad * 8;
      float4 fA = *(const float4*)(wp);
      float4 fB = *(const float4*)(wp + 4);
      union { bf16x8 v8; s16x4 h[2]; } u;
      u.h[0].x = (short)f2bf(fA.x); u.h[0].y = (short)f2bf(fA.y);
      u.h[0].z = (short)f2bf(fA.z); u.h[0].w = (short)f2bf(fA.w);
      u.h[1].x = (short)f2bf(fB.x); u.h[1].y = (short)f2bf(fB.y);
      u.h[1].z = (short)f2bf(fB.z); u.h[1].w = (short)f2bf(fB.w);
      barr[ct][ks] = u.v8;
    }
  }

  // this lane finishes col-tiles 2wv and 2wv+1 after the k-reduction
  const int j0 = jg * JT + wv * 32 + l15;
  const int j1 = j0 + 16;
  const float whx0 = Whx[j0], whx1 = Whx[j1];
  const float bhv0 = bh[j0],  bhv1 = bh[j1];

  // exchange thread mapping: 16 rows x 16 segs x 16 B
  const int sr  = tid >> 4;               // 0..15 row
  const int seg = tid & 15;               // 0..15

  int* myflags = flags + bg * 64;         // 8 flags, one 256B line per bg

  for (int t = 0; t < SEQ; ++t) {
    const unsigned short* hin = hbuf + ((t + 1) & 1) * HBUF_HALVES;
    unsigned short*      hout = hbuf + (t & 1) * HBUF_HALVES;

    f32x4 acc0 = {0,0,0,0}, acc1 = {0,0,0,0}, acc2 = {0,0,0,0}, acc3 = {0,0,0,0};
    f32x4 acc4 = {0,0,0,0}, acc5 = {0,0,0,0}, acc6 = {0,0,0,0}, acc7 = {0,0,0,0};

    // x for this step: rows bg*16 + quad*4 + rg
    float xv[4];
    {
      const float* xp = x + (bg * BT + quad * 4) * SEQ + t;
#pragma unroll
      for (int rg = 0; rg < 4; ++rg) xv[rg] = xp[rg * SEQ];
    }

    if (t > 0) {
      // acquire (R2-verified): wait for all 8 peers of this batch-group
      if (tid < GJ) {
        while (load_flag(myflags + tid) < t) {
          asm volatile("s_sleep 1" ::: "memory");
        }
      }
      // kill this CU's stale L1 lines of hin (read at t-2); same-XCD L2 is
      // fresh via producers' sc0 sc1 write-through. [R7-verified combo]
      if (tid == 0) l1_inv_wait();
      __syncthreads();   // inv + spins complete before any wave's A loads

      // A fragments direct from global in MFMA layout (PLAIN loads -> L2 hit):
      // row l15 (BT=16: one row-tile), k-halves = wv*256 + quad*8 + ks*32.
      const short* pA = (const short*)hin + (bg * BT + l15) * HID
                        + wv * 256 + quad * 8;
      i32x4 A0, A1, A2, A3, A4, A5, A6, A7;
      issue4_64(pA,       A0, A1, A2, A3);   // ks 0..3 (byte stride 64)
      issue4_64(pA + 128, A4, A5, A6, A7);   // ks 4..7 (pA+128 halves = +256 B)

      // TIED wait (rule #18): bind every A reg so MFMAs can't hoist above it.
      asm volatile("s_waitcnt vmcnt(0)"
                   : "+v"(A0), "+v"(A1), "+v"(A2), "+v"(A3),
                     "+v"(A4), "+v"(A5), "+v"(A6), "+v"(A7)
                   :: "memory");
      __builtin_amdgcn_sched_barrier(0);

#define KSTEP(Ar, KS) { \
      bf16x8 _a = *(const bf16x8*)&(Ar); \
      acc0 = MFMA(_a, barr[0][KS], acc0); acc1 = MFMA(_a, barr[1][KS], acc1); \
      acc2 = MFMA(_a, barr[2][KS], acc2); acc3 = MFMA(_a, barr[3][KS], acc3); \
      acc4 = MFMA(_a, barr[4][KS], acc4); acc5 = MFMA(_a, barr[5][KS], acc5); \
      acc6 = MFMA(_a, barr[6][KS], acc6); acc7 = MFMA(_a, barr[7][KS], acc7); }
      KSTEP(A0, 0) KSTEP(A1, 1) KSTEP(A2, 2) KSTEP(A3, 3)
      KSTEP(A4, 4) KSTEP(A5, 5) KSTEP(A6, 6) KSTEP(A7, 7)
#undef KSTEP
    }

    // ---- cross-wave k-reduction: scr[(ct*4 + wv)*64 + lane] (f32x4 slots) ----
    barrier_lgkm();   // prior-step scratch/hS readers done
#pragma unroll
    for (int ct = 0; ct < 8; ++ct) {
      f32x4 w = (ct == 0) ? acc0 : (ct == 1) ? acc1 : (ct == 2) ? acc2 :
                (ct == 3) ? acc3 : (ct == 4) ? acc4 : (ct == 5) ? acc5 :
                (ct == 6) ? acc6 : acc7;
      *(f32x4*)(scr + ((ct * 4 + wv) * 64 + lane) * 4) = w;
    }
    barrier_lgkm();
    {
      f32x4 f0 = {0,0,0,0}, f1 = {0,0,0,0};
#pragma unroll
      for (int w = 0; w < 4; ++w) {
        f0 += *(const f32x4*)(scr + (((2 * wv)     * 4 + w) * 64 + lane) * 4);
        f1 += *(const f32x4*)(scr + (((2 * wv + 1) * 4 + w) * 64 + lane) * 4);
      }
      // h = tanh(acc + x*whx + bh) -> hS (wave wv owns col-tiles 2wv, 2wv+1)
#pragma unroll
      for (int rg = 0; rg < 4; ++rg) {
        float z0 = f0[rg] + xv[rg] * whx0 + bhv0;
        hS[(quad * 4 + rg) * HSTR + wv * 32 + l15] = (short)f2bf(tanh_fast(z0));
        float z1 = f1[rg] + xv[rg] * whx1 + bhv1;
        hS[(quad * 4 + rg) * HSTR + wv * 32 + 16 + l15] = (short)f2bf(tanh_fast(z1));
      }
    }
    barrier_lgkm();   // hS complete
    {
      const short* hsrc = hS + sr * HSTR + seg * 8;
      u32x2 lo = *(const u32x2*)(hsrc);
      u32x2 hi = *(const u32x2*)(hsrc + 4);
      i32x4 sv; sv.x = (int)lo.x; sv.y = (int)lo.y; sv.z = (int)hi.x; sv.w = (int)hi.y;
      unsigned short* dst = hout + (bg * BT + sr) * HID + jg * JT + seg * 8;
      store16(dst, sv);
    }
    waitcnt0();          // this thread's coalesced store retired at MALL
    barrier_lgkm();      // all threads retired before the flag release
    if (tid == 0) store_flag(myflags + jg, t + 1);
  }

  // ---- output head: out[b, jg*16+cc] = h_last . W_ph[c] + b_p ----
  if (tid < GJ) {
    while (load_flag(myflags + tid) < SEQ) {
      asm volatile("s_sleep 1" ::: "memory");
    }
  }
  __syncthreads();

  // stage h_last (16 x 1024 bf16 = 32KB) into smem: thread (sr, seg) owns the
  // CONTIGUOUS 128 B at row sr, bytes seg*128..+128 (16B-stride loads).
  const unsigned short* hlast = hbuf + ((SEQ - 1) & 1) * HBUF_HALVES;
  {
    const char* lbase = (const char*)(hlast + (bg * BT + sr) * HID) + seg * 128;
    i32x4 p0, p1, p2, p3, p4, p5, p6, p7;
    issue4_16(lbase,      p0, p1, p2, p3);   // bytes 0,16,32,48
    issue4_16(lbase + 64, p4, p5, p6, p7);   // bytes 64,80,96,112
    waitcnt0();
    short* sdst = smem + sr * 1028 + seg * 64;   // [16][1028] halves
    wr16(sdst,      p0); wr16(sdst + 8,  p1); wr16(sdst + 16, p2); wr16(sdst + 24, p3);
    wr16(sdst + 32, p4); wr16(sdst + 40, p5); wr16(sdst + 48, p6); wr16(sdst + 56, p7);
  }
  __syncthreads();
  {
    const int hr = tid >> 4;            // 0..15 batch row
    const int cc = tid & 15;            // 0..15 class col within slice
    const int cg = jg * 16 + cc;
    const float* wp = Wph + cg * HID;
    const short* hs = smem + hr * 1028;
    float acc = 0.f;
#pragma unroll 8
    for (int k4 = 0; k4 < 256; ++k4) {
      float4 w  = *(const float4*)(wp + k4 * 4);
      s16x4 hv  = *(const s16x4*)(hs + k4 * 4);
      acc += b2f(hv.x) * w.x + b2f(hv.y) * w.y + b2f(hv.z) * w.z + b2f(hv.w) * w.w;
    }
    out[(bg * BT + hr) * CLS + cg] = acc + bp[cg];
  }
}

extern "C" void kernel_launch(void* const* d_in, const int* in_sizes, int n_in,
                              void* d_out, int out_size, void* d_ws, size_t ws_size,
                              hipStream_t stream) {
  const float* x   = (const float*)d_in[0];
  const float* Whx = (const float*)d_in[1];
  const float* Whh = (const float*)d_in[2];
  const float* bh  = (const float*)d_in[3];
  const float* Wph = (const float*)d_in[4];
  const float* bp  = (const float*)d_in[5];
  float* out = (float*)d_out;

  unsigned short* hbuf = (unsigned short*)d_ws;
  int* flags = (int*)((char*)d_ws + (size_t)2 * HBUF_HALVES * 2);

  // Zero flags each launch (stream-ordered, capture-safe): closes the
  // cross-launch race where stale flags (=SEQ) would let consumers run ahead.
  hipMemsetAsync(flags, 0, GB * 64 * sizeof(int), stream);

  hipFuncSetAttribute(reinterpret_cast<const void*>(rnn_persistent),
                      hipFuncAttributeMaxDynamicSharedMemorySize, SMEM_BYTES);

  rnn_persistent<<<dim3(GB * GJ), dim3(256), SMEM_BYTES, stream>>>(
      x, Whx, Whh, bh, Wph, bp, out, hbuf, flags);
}